// Round 2
// baseline (427.078 us; speedup 1.0000x reference)
//
#include <hip/hip_runtime.h>
#include <hip/hip_bf16.h>
#include <hip/hip_fp16.h>

#define T_DIM 2048
#define B_DIM 32
#define LIS_DIM 1024
#define SPE_DIM 1024
#define ATT_DIM 512

typedef _Float16 f16x8 __attribute__((ext_vector_type(8)));
typedef _Float16 f16x4 __attribute__((ext_vector_type(4)));
typedef float f32x4 __attribute__((ext_vector_type(4)));

// K0: WT[c][k] f16; c<512 -> W_score[k][c], c>=512 -> W_value[k][c-512]
__global__ void transpose_w_kernel(const float* __restrict__ Ws,
                                   const float* __restrict__ Wv,
                                   _Float16* __restrict__ WT) {
  __shared__ float tile[32][33];
  int id = blockIdx.x;            // 1024 blocks
  int mat = id >> 9;              // 512 tiles per matrix
  int r = id & 511;
  int ktile = r & 31;             // 32 tiles along k (1024)
  int ctile = r >> 5;             // 16 tiles along c (512)
  const float* W = mat ? Wv : Ws;
  int k0 = ktile * 32, c0 = ctile * 32;
  int j = threadIdx.x & 31, i0 = threadIdx.x >> 5;
  for (int i = i0; i < 32; i += 8)
    tile[i][j] = W[(size_t)(k0 + i) * ATT_DIM + c0 + j];
  __syncthreads();
  for (int i = i0; i < 32; i += 8)
    WT[(size_t)(mat * ATT_DIM + c0 + i) * LIS_DIM + k0 + j] = (_Float16)tile[j][i];
}

// K1: q[b][a] = relu(spe[b]·W_proj[:,a] + b_proj[a]), f32
__global__ void query_kernel(const float* __restrict__ spe,
                             const float* __restrict__ Wp,
                             const float* __restrict__ bp,
                             float* __restrict__ q) {
  __shared__ float s[SPE_DIM];
  int b = blockIdx.x;
  for (int i = threadIdx.x; i < SPE_DIM; i += 256) s[i] = spe[(size_t)b * SPE_DIM + i];
  __syncthreads();
  for (int a = threadIdx.x; a < ATT_DIM; a += 256) {
    float acc = bp[a];
    for (int l = 0; l < SPE_DIM; ++l)
      acc = fmaf(s[l], Wp[(size_t)l * ATT_DIM + a], acc);
    q[(size_t)b * ATT_DIM + a] = fmaxf(acc, 0.f);
  }
}

// K2 (SCORES) / K4 (!SCORES): 64 rows of X (one b, 64 t's), BK=256 double-buffered
// f16 LDS staging, 8 waves x 64 cols, 16x16x32 f16 MFMA, fused epilogues.
template <bool SCORES>
__global__ __launch_bounds__(512, 1)
void fused_gemm_kernel(const float* __restrict__ x,
                       const _Float16* __restrict__ WTbase,  // already offset for value half
                       const float* __restrict__ bias,
                       const float* __restrict__ qrow,       // SCORES: q f32 [32][512]
                       const float* __restrict__ attn,       // !SCORES: attn f32 [32][2048]
                       float* __restrict__ scores,           // SCORES out: f32 [32][2048]
                       float* __restrict__ ctx) {            // !SCORES out: f32 [32][512] (atomic)
  __shared__ __align__(16) char A_lds[2][32768];  // 64 rows x 256 f16, XOR-swizzled
  __shared__ float bias_s[ATT_DIM];
  __shared__ float w_s[ATT_DIM];
  __shared__ float red_s[64];

  const int tid = threadIdx.x;
  const int blk = blockIdx.x;
  const int b = blk & 31;
  const int t0 = (blk >> 5) * 64;

  bias_s[tid] = bias[tid];
  if (SCORES) {
    w_s[tid] = qrow[(size_t)b * ATT_DIM + tid];
  } else if (tid < 64) {
    w_s[tid] = attn[(size_t)b * T_DIM + t0 + tid];
  }
  if (tid < 64) red_s[tid] = 0.f;

  const float* xb = x + (size_t)b * LIS_DIM;

  // stage chunk c (k in [c*256, c*256+256)) into buf
  auto stage = [&](int c, char* buf) {
    const int k0 = c * 256;
#pragma unroll
    for (int it = 0; it < 8; ++it) {
      int idx = it * 512 + tid;    // 4096 float4 = 64 rows x 64 float4
      int row = idx >> 6;
      int c4 = idx & 63;
      const float4 f =
          ((const float4*)(xb + (size_t)(t0 + row) * (B_DIM * LIS_DIM) + k0))[c4];
      f16x4 h;
      h[0] = (_Float16)f.x; h[1] = (_Float16)f.y;
      h[2] = (_Float16)f.z; h[3] = (_Float16)f.w;
      int off = row * 512 + c4 * 8;
      off ^= (row & 7) << 4;
      *(f16x4*)(buf + off) = h;
    }
  };

  const int wv = tid >> 6;
  const int lane = tid & 63;
  const int lo = lane & 15;
  const int hi = lane >> 4;
  const int colBase = wv * 64;

  f32x4 acc[4][4];
#pragma unroll
  for (int m = 0; m < 4; ++m)
#pragma unroll
    for (int n = 0; n < 4; ++n)
      acc[m][n] = (f32x4){0.f, 0.f, 0.f, 0.f};

  const _Float16* Bp = WTbase + (size_t)colBase * LIS_DIM;

  stage(0, A_lds[0]);
  __syncthreads();

  for (int c = 0; c < 4; ++c) {
    if (c < 3) stage(c + 1, A_lds[(c + 1) & 1]);
    const char* buf = A_lds[c & 1];
    const int kbase = c * 256;
#pragma unroll
    for (int kk = 0; kk < 256; kk += 32) {
      f16x8 af[4], bf[4];
#pragma unroll
      for (int m = 0; m < 4; ++m) {
        int row = m * 16 + lo;
        int off = row * 512 + kk * 2 + hi * 16;
        off ^= (row & 7) << 4;
        af[m] = *(const f16x8*)(buf + off);
      }
#pragma unroll
      for (int n = 0; n < 4; ++n)
        bf[n] = *(const f16x8*)(Bp + (size_t)(n * 16 + lo) * LIS_DIM + kbase + kk + hi * 8);
#pragma unroll
      for (int m = 0; m < 4; ++m)
#pragma unroll
        for (int n = 0; n < 4; ++n)
          acc[m][n] = __builtin_amdgcn_mfma_f32_16x16x32_f16(af[m], bf[n], acc[m][n], 0, 0, 0);
    }
    __syncthreads();
  }

  if (SCORES) {
    // score[row] += sum_col q[col] * relu(keys[row][col] + bias[col])
    float sr[4][4] = {};
#pragma unroll
    for (int m = 0; m < 4; ++m)
#pragma unroll
      for (int n = 0; n < 4; ++n) {
        int col = colBase + n * 16 + lo;
        float qv = w_s[col], bb = bias_s[col];
#pragma unroll
        for (int r = 0; r < 4; ++r) {
          float kv = fmaxf(acc[m][n][r] + bb, 0.f);
          sr[m][r] += kv * qv;
        }
      }
#pragma unroll
    for (int m = 0; m < 4; ++m)
#pragma unroll
      for (int r = 0; r < 4; ++r) {
        float v = sr[m][r];
        v += __shfl_xor(v, 1, 64);
        v += __shfl_xor(v, 2, 64);
        v += __shfl_xor(v, 4, 64);
        v += __shfl_xor(v, 8, 64);
        if (lo == 0) atomicAdd(&red_s[m * 16 + hi * 4 + r], v);
      }
    __syncthreads();
    if (tid < 64) scores[(size_t)b * T_DIM + t0 + tid] = red_s[tid];
  } else {
    // ctx[b][col] += sum_row attn[row] * relu(vals[row][col] + bias[col])
    float cs[4] = {0.f, 0.f, 0.f, 0.f};
#pragma unroll
    for (int m = 0; m < 4; ++m)
#pragma unroll
      for (int r = 0; r < 4; ++r) {
        float w = w_s[m * 16 + hi * 4 + r];
#pragma unroll
        for (int n = 0; n < 4; ++n) {
          int col = colBase + n * 16 + lo;
          float v = fmaxf(acc[m][n][r] + bias_s[col], 0.f);
          cs[n] += w * v;
        }
      }
#pragma unroll
    for (int n = 0; n < 4; ++n) {
      cs[n] += __shfl_xor(cs[n], 16, 64);
      cs[n] += __shfl_xor(cs[n], 32, 64);
      if (hi == 0) atomicAdd(&ctx[(size_t)b * ATT_DIM + colBase + n * 16 + lo], cs[n]);
    }
  }
}

// K3: masked softmax per b; writes attn f32 to out, zeroes context region of out
__global__ void softmax_kernel(const float* __restrict__ scores,
                               const int* __restrict__ llen,
                               float* __restrict__ attn_out,   // d_out + 16384
                               float* __restrict__ ctx_out) {  // d_out (zeroed here)
  __shared__ float rmax[4], rsum[4];
  int b = blockIdx.x, tid = threadIdx.x;
  int L = llen[b];
  float v[8];
  float mx = -1e30f;
  for (int i = 0; i < 8; ++i) {
    int t = i * 256 + tid;
    float s = scores[(size_t)b * T_DIM + t];
    if (t >= L) s -= 100.f;     // additive mask, faithful to reference
    v[i] = s;
    mx = fmaxf(mx, s);
  }
  for (int d = 1; d < 64; d <<= 1) mx = fmaxf(mx, __shfl_xor(mx, d, 64));
  if ((tid & 63) == 0) rmax[tid >> 6] = mx;
  __syncthreads();
  mx = fmaxf(fmaxf(rmax[0], rmax[1]), fmaxf(rmax[2], rmax[3]));
  float sum = 0.f;
  for (int i = 0; i < 8; ++i) { v[i] = expf(v[i] - mx); sum += v[i]; }
  for (int d = 1; d < 64; d <<= 1) sum += __shfl_xor(sum, d, 64);
  if ((tid & 63) == 0) rsum[tid >> 6] = sum;
  __syncthreads();
  sum = rsum[0] + rsum[1] + rsum[2] + rsum[3];
  float inv = 1.f / sum;
  for (int i = 0; i < 8; ++i) {
    int t = i * 256 + tid;
    attn_out[(size_t)b * T_DIM + t] = v[i] * inv;
  }
  for (int i = tid; i < ATT_DIM; i += 256) ctx_out[(size_t)b * ATT_DIM + i] = 0.f;
}

extern "C" void kernel_launch(void* const* d_in, const int* in_sizes, int n_in,
                              void* d_out, int out_size, void* d_ws, size_t ws_size,
                              hipStream_t stream) {
  const float* x   = (const float*)d_in[0];
  const float* spe = (const float*)d_in[1];
  const int*   len = (const int*)d_in[2];
  const float* Ws  = (const float*)d_in[4];
  const float* bs  = (const float*)d_in[5];
  const float* Wv  = (const float*)d_in[6];
  const float* bv  = (const float*)d_in[7];
  const float* Wp  = (const float*)d_in[8];
  const float* bp  = (const float*)d_in[9];
  float* out = (float*)d_out;  // [0,16384): context f32, [16384,81920): attn f32

  char* ws = (char*)d_ws;
  _Float16* WT  = (_Float16*)ws;                             // 2 MB
  float* q      = (float*)(ws + (2u << 20));                 // 64 KB
  float* scores = (float*)(ws + (2u << 20) + (64u << 10));   // 256 KB

  transpose_w_kernel<<<dim3(1024), dim3(256), 0, stream>>>(Ws, Wv, WT);
  query_kernel<<<dim3(32), dim3(256), 0, stream>>>(spe, Wp, bp, q);
  fused_gemm_kernel<true><<<dim3(1024), dim3(512), 0, stream>>>(
      x, WT, bs, q, nullptr, scores, nullptr);
  softmax_kernel<<<dim3(32), dim3(256), 0, stream>>>(scores, len, out + 16384, out);
  fused_gemm_kernel<false><<<dim3(1024), dim3(512), 0, stream>>>(
      x, WT + (size_t)ATT_DIM * LIS_DIM, bv, nullptr, out + 16384, nullptr, out);
}